// Round 2
// baseline (335.377 us; speedup 1.0000x reference)
//
#include <hip/hip_runtime.h>
#include <stdint.h>

#define B_ 4
#define N_ 4096
#define C_ 256
#define CK_ 32
#define LOG2E 1.44269504088896340736f
#define SOFT_OFF 88.0f

typedef float f32x4 __attribute__((ext_vector_type(4)));
typedef short s16x8 __attribute__((ext_vector_type(8)));
typedef __bf16 bf16x8 __attribute__((ext_vector_type(8)));

static __device__ __forceinline__ unsigned short f2bf(float f) {
    union { float f; uint32_t u; } v; v.f = f;
    return (unsigned short)((v.u + 0x7FFFu + ((v.u >> 16) & 1u)) >> 16);
}
static __device__ __forceinline__ float bf2f(unsigned short h) {
    union { uint32_t u; float f; } v; v.u = ((uint32_t)h) << 16;
    return v.f;
}
static __device__ __forceinline__ bf16x8 as_bf(s16x8 v) {
    return __builtin_bit_cast(bf16x8, v);
}

// ---------------- projection v2: LDS-staged weights, 32 rows/block ----------
// 256 threads; tid&63 -> col set {c(f/g), c+64i (h)}, tid>>6 -> row octet.
__global__ __launch_bounds__(256) void proj_kernel(
    const float* __restrict__ x,
    const float* __restrict__ Wf, const float* __restrict__ bfp,
    const float* __restrict__ Wg, const float* __restrict__ bgp,
    const float* __restrict__ Wh, const float* __restrict__ bhp,
    unsigned short* __restrict__ q_hi, unsigned short* __restrict__ q_lo,
    unsigned short* __restrict__ k_hi, unsigned short* __restrict__ k_lo,
    unsigned short* __restrict__ v_t)
{
    __shared__ __align__(16) float xs[32 * 256];     // 32 KB
    __shared__ __align__(16) float wts[320 * 20];    // [col][k-in-chunk], 25.6 KB

    const int tid = threadIdx.x;
    const int row0 = blockIdx.x * 32;
    const int c = tid & 63;
    const int rg = tid >> 6;

    // stage x tile (coalesced f32x4)
    const float* xsrc = x + (size_t)row0 * C_;
    #pragma unroll
    for (int i = 0; i < 8; i++)
        ((f32x4*)xs)[tid + 256 * i] = ((const f32x4*)xsrc)[tid + 256 * i];

    // per-thread weight-staging slots (5 f32x4 each), hoisted out of the loop
    const float* sbase[5]; int soff[5], sstep[5], dcol[5], srow[5];
    #pragma unroll
    for (int j = 0; j < 5; j++) {
        int idx = tid + 256 * j;
        int r = idx / 80, part = idx % 80;
        srow[j] = r;
        if (part < 8)       { sbase[j] = Wf; soff[j] = r * 32 + part * 4;          sstep[j] = 16 * 32;  dcol[j] = part * 4; }
        else if (part < 16) { sbase[j] = Wg; soff[j] = r * 32 + (part - 8) * 4;    sstep[j] = 16 * 32;  dcol[j] = 32 + (part - 8) * 4; }
        else                { sbase[j] = Wh; soff[j] = r * 256 + (part - 16) * 4;  sstep[j] = 16 * 256; dcol[j] = 64 + (part - 16) * 4; }
    }

    const float bias0 = (c < 32) ? bfp[c] : bgp[c - 32];
    float biash[4];
    #pragma unroll
    for (int i = 0; i < 4; i++) biash[i] = bhp[c + 64 * i];

    float acc0[8]; float acch[4][8];
    #pragma unroll
    for (int r = 0; r < 8; r++) { acc0[r] = 0.f;
        #pragma unroll
        for (int i = 0; i < 4; i++) acch[i][r] = 0.f; }

    for (int ch = 0; ch < 16; ch++) {      // 16 k-chunks of 16
        __syncthreads();                   // prev chunk's readers done (covers xs on ch=0)
        #pragma unroll
        for (int j = 0; j < 5; j++) {
            f32x4 wv = *(const f32x4*)(sbase[j] + (size_t)ch * sstep[j] + soff[j]);
            int dc = dcol[j], rr = srow[j];
            wts[(dc + 0) * 20 + rr] = wv.x;
            wts[(dc + 1) * 20 + rr] = wv.y;
            wts[(dc + 2) * 20 + rr] = wv.z;
            wts[(dc + 3) * 20 + rr] = wv.w;
        }
        __syncthreads();
        #pragma unroll
        for (int k4 = 0; k4 < 4; k4++) {
            f32x4 w0 = *(const f32x4*)(wts + c * 20 + k4 * 4);
            f32x4 wh4[4];
            #pragma unroll
            for (int i = 0; i < 4; i++)
                wh4[i] = *(const f32x4*)(wts + (64 + c + 64 * i) * 20 + k4 * 4);
            #pragma unroll
            for (int r = 0; r < 8; r++) {
                f32x4 xv = *(const f32x4*)(xs + (rg * 8 + r) * 256 + ch * 16 + k4 * 4);
                acc0[r] += xv.x * w0.x + xv.y * w0.y + xv.z * w0.z + xv.w * w0.w;
                #pragma unroll
                for (int i = 0; i < 4; i++)
                    acch[i][r] += xv.x * wh4[i].x + xv.y * wh4[i].y
                                + xv.z * wh4[i].z + xv.w * wh4[i].w;
            }
        }
    }

    const int b = row0 / N_, n0 = (row0 % N_) + rg * 8;
    {   // f -> key arrays, g -> query arrays, hi/lo split for fp32-accurate scores
        unsigned short* hi_dst = (c < 32) ? k_hi : q_hi;
        unsigned short* lo_dst = (c < 32) ? k_lo : q_lo;
        const int cc = (c < 32) ? c : c - 32;
        #pragma unroll
        for (int r = 0; r < 8; r++) {
            float v = acc0[r] + bias0;
            unsigned short hi = f2bf(v);
            unsigned short lo = f2bf(v - bf2f(hi));
            size_t o = ((size_t)(b * N_ + n0 + r)) * CK_ + cc;
            hi_dst[o] = hi; lo_dst[o] = lo;
        }
    }
    #pragma unroll
    for (int i = 0; i < 4; i++) {
        union { s16x8 v; unsigned short u[8]; } pk;
        #pragma unroll
        for (int r = 0; r < 8; r++) pk.u[r] = f2bf(acch[i][r] + biash[i]);
        *(s16x8*)(v_t + ((size_t)b * C_ + (c + 64 * i)) * N_ + n0) = pk.v;
    }
}

// ---------------- flash attention v2: 512 thr, 2 channel-split groups -------
// grid (N_/64, B_). Waves 0-3 = group 0 (channels 0..127), waves 4-7 = group 1
// (channels 128..255). Both groups compute QK+softmax redundantly (cheap);
// each stages/consumes only its half of h^T. Fixed-offset exp2 softmax (no
// per-iter max reduction): p = 2^(s*log2e - 88); exact softmax ratio, safe
// since |s| <= |g||f| < ~80 << 149 (overflow) and row-max >> -26 (underflow).
__global__ __launch_bounds__(512) void attn_kernel(
    const unsigned short* __restrict__ q_hi, const unsigned short* __restrict__ q_lo,
    const unsigned short* __restrict__ k_hi, const unsigned short* __restrict__ k_lo,
    const unsigned short* __restrict__ v_t,
    const float* __restrict__ x, const float* __restrict__ gamma_p,
    float* __restrict__ out)
{
    // 61440 B total: keys 10 KB | hT 2x16 KB (XOR-swizzled, no pad) | P 8x2.25 KB
    __shared__ __align__(16) unsigned short smem[30720];
    unsigned short* fhi_s   = smem;                    // 64 x 40
    unsigned short* flo_s   = smem + 2560;             // 64 x 40
    unsigned short* hT_base = smem + 5120;             // 2 x (128ch x 64k)
    unsigned short* P_base  = smem + 5120 + 16384;     // 8 waves x (16 x 72)

    const int tid  = threadIdx.x;
    const int lane = tid & 63;
    const int wave = tid >> 6;
    const int g    = wave >> 2;        // channel-split group
    const int w    = wave & 3;         // q-subtile within block
    const int col  = lane & 15;
    const int quad = lane >> 4;
    const int qt = blockIdx.x;
    const int b  = blockIdx.y;

    unsigned short* hTg = hT_base + g * 8192;
    unsigned short* Pw  = P_base + wave * 1152;

    // hT staging assignment: 2 threads per channel
    const int sch = tid >> 1, shalf = tid & 1;
    unsigned short* hTd = hT_base + (sch >> 7) * 8192 + (sch & 127) * 64;
    const int swz = sch & 7;

    // Q A-fragments (hi/lo): A[m=col][k=quad*8+j], one frag spans Ck=32
    const size_t qoff = ((size_t)(b * N_ + qt * 64 + w * 16 + col)) * CK_ + quad * 8;
    const bf16x8 aQh = as_bf(*(const s16x8*)(q_hi + qoff));
    const bf16x8 aQl = as_bf(*(const s16x8*)(q_lo + qoff));

    f32x4 acc[8];
    #pragma unroll
    for (int nt = 0; nt < 8; nt++) acc[nt] = (f32x4){0.f, 0.f, 0.f, 0.f};
    float l_r[4] = {0.f, 0.f, 0.f, 0.f};

    for (int kt = 0; kt < N_ / 64; kt++) {
        __syncthreads();   // all waves done with previous tile's LDS
        if (tid < 256) {   // stage key tile hi+lo (wave-uniform branch)
            const s16x8* sh = (const s16x8*)(k_hi + ((size_t)(b * N_ + kt * 64)) * CK_);
            const s16x8* sl = (const s16x8*)(k_lo + ((size_t)(b * N_ + kt * 64)) * CK_);
            s16x8 vh = sh[tid], vl = sl[tid];
            const int fr = tid >> 2, fc = (tid & 3) * 8;
            *(s16x8*)(fhi_s + fr * 40 + fc) = vh;
            *(s16x8*)(flo_s + fr * 40 + fc) = vl;
        }
        {   // stage h^T half-tile for own group, XOR-swizzled chunks
            const s16x8* sv = (const s16x8*)(v_t + ((size_t)b * C_ + sch) * N_
                                             + (size_t)kt * 64 + shalf * 32);
            #pragma unroll
            for (int j = 0; j < 4; j++) {
                int i = shalf * 4 + j;
                *(s16x8*)(hTd + ((i ^ swz) * 8)) = sv[j];
            }
        }
        __syncthreads();

        // S = Q K^T (hi/lo split => fp32-accurate logits)
        f32x4 sc[4];
        #pragma unroll
        for (int t = 0; t < 4; t++) {
            bf16x8 bh = as_bf(*(const s16x8*)(fhi_s + (t * 16 + col) * 40 + quad * 8));
            bf16x8 bl = as_bf(*(const s16x8*)(flo_s + (t * 16 + col) * 40 + quad * 8));
            f32x4 s = (f32x4){0.f, 0.f, 0.f, 0.f};
            s = __builtin_amdgcn_mfma_f32_16x16x32_bf16(aQh, bh, s, 0, 0, 0);
            s = __builtin_amdgcn_mfma_f32_16x16x32_bf16(aQl, bh, s, 0, 0, 0);
            s = __builtin_amdgcn_mfma_f32_16x16x32_bf16(aQh, bl, s, 0, 0, 0);
            sc[t] = s;
        }

        // fixed-offset exp2 softmax numerator; per-lane l accumulation only
        float p[4][4];
        #pragma unroll
        for (int t = 0; t < 4; t++)
            #pragma unroll
            for (int r = 0; r < 4; r++)
                p[t][r] = __builtin_amdgcn_exp2f(fmaf(sc[t][r], LOG2E, -SOFT_OFF));
        #pragma unroll
        for (int r = 0; r < 4; r++)
            l_r[r] += (p[0][r] + p[1][r]) + (p[2][r] + p[3][r]);

        // P: C-layout -> row-major LDS, adjacent cols packed to b32 via shfl
        #pragma unroll
        for (int t = 0; t < 4; t++)
            #pragma unroll
            for (int r = 0; r < 4; r++) {
                uint32_t v = f2bf(p[t][r]);
                uint32_t o = (uint32_t)__shfl_xor((int)v, 1, 64);
                if (!(col & 1))
                    *(uint32_t*)(Pw + (quad * 4 + r) * 72 + t * 16 + col)
                        = v | (o << 16);
            }
        // per-wave P buffer: same-wave lgkmcnt ordering suffices, no barrier
        const bf16x8 aP0 = as_bf(*(const s16x8*)(Pw + col * 72 + quad * 8));
        const bf16x8 aP1 = as_bf(*(const s16x8*)(Pw + col * 72 + 32 + quad * 8));

        // O += P V over this group's 8 channel tiles (swizzled b128 reads)
        #pragma unroll
        for (int nt = 0; nt < 8; nt++) {
            int ch = nt * 16 + col;
            bf16x8 bv0 = as_bf(*(const s16x8*)(hTg + ch * 64 + ((quad ^ (ch & 7)) * 8)));
            bf16x8 bv1 = as_bf(*(const s16x8*)(hTg + ch * 64 + (((quad + 4) ^ (ch & 7)) * 8)));
            acc[nt] = __builtin_amdgcn_mfma_f32_16x16x32_bf16(aP0, bv0, acc[nt], 0, 0, 0);
            acc[nt] = __builtin_amdgcn_mfma_f32_16x16x32_bf16(aP1, bv1, acc[nt], 0, 0, 0);
        }
    }

    // one-time l reduction across the 16 cols, then fused epilogue
    #pragma unroll
    for (int off = 1; off < 16; off <<= 1)
        #pragma unroll
        for (int r = 0; r < 4; r++)
            l_r[r] += __shfl_xor(l_r[r], off, 64);

    const float gamma = *gamma_p;
    float rcp[4];
    #pragma unroll
    for (int r = 0; r < 4; r++) rcp[r] = 1.0f / l_r[r];
    #pragma unroll
    for (int nt = 0; nt < 8; nt++)
        #pragma unroll
        for (int r = 0; r < 4; r++) {
            size_t idx = ((size_t)(b * N_ + qt * 64 + w * 16 + quad * 4 + r)) * C_
                       + g * 128 + nt * 16 + col;
            out[idx] = gamma * (acc[nt][r] * rcp[r]) + x[idx];
        }
}

extern "C" void kernel_launch(void* const* d_in, const int* in_sizes, int n_in,
                              void* d_out, int out_size, void* d_ws, size_t ws_size,
                              hipStream_t stream) {
    const float* x   = (const float*)d_in[0];
    const float* Wf  = (const float*)d_in[1];
    const float* bfp = (const float*)d_in[2];
    const float* Wg  = (const float*)d_in[3];
    const float* bgp = (const float*)d_in[4];
    const float* Wh  = (const float*)d_in[5];
    const float* bhp = (const float*)d_in[6];
    const float* gam = (const float*)d_in[7];
    float* out = (float*)d_out;

    unsigned char* ws = (unsigned char*)d_ws;
    const size_t MB = 1 << 20;
    unsigned short* q_hi = (unsigned short*)(ws + 0 * MB);  // [B][N][32] bf16 bits
    unsigned short* q_lo = (unsigned short*)(ws + 1 * MB);
    unsigned short* k_hi = (unsigned short*)(ws + 2 * MB);
    unsigned short* k_lo = (unsigned short*)(ws + 3 * MB);
    unsigned short* v_t  = (unsigned short*)(ws + 4 * MB);  // [B][C][N] bf16 bits, 8 MB

    proj_kernel<<<dim3(B_ * N_ / 32), dim3(256), 0, stream>>>(
        x, Wf, bfp, Wg, bgp, Wh, bhp, q_hi, q_lo, k_hi, k_lo, v_t);
    attn_kernel<<<dim3(N_ / 64, B_), dim3(512), 0, stream>>>(
        q_hi, q_lo, k_hi, k_lo, v_t, x, gam, out);
}

// Round 3
// 303.493 us; speedup vs baseline: 1.1051x; 1.1051x over previous
//
#include <hip/hip_runtime.h>
#include <stdint.h>

#define B_ 4
#define N_ 4096
#define C_ 256
#define LOG2E 1.44269504088896340736f
#define SOFT_OFF 88.0f

typedef float f32x4 __attribute__((ext_vector_type(4)));
typedef float f32x16 __attribute__((ext_vector_type(16)));
typedef short s16x8 __attribute__((ext_vector_type(8)));
typedef __bf16 bf16x8 __attribute__((ext_vector_type(8)));
typedef _Float16 f16x8 __attribute__((ext_vector_type(8)));

static __device__ __forceinline__ unsigned short f2bf(float f) {
    union { float f; uint32_t u; } v; v.f = f;
    return (unsigned short)((v.u + 0x7FFFu + ((v.u >> 16) & 1u)) >> 16);
}
static __device__ __forceinline__ bf16x8 as_bf(s16x8 v) {
    return __builtin_bit_cast(bf16x8, v);
}

// ---------- wprep: W -> WT f16 [320][256]  (cols: 0-31 f, 32-63 g, 64-319 h) ----
__global__ __launch_bounds__(256) void wprep(
    const float* __restrict__ Wf, const float* __restrict__ Wg,
    const float* __restrict__ Wh, _Float16* __restrict__ WT)
{
    int idx = blockIdx.x * 256 + threadIdx.x;   // 320*256 total
    int c = idx >> 8, k = idx & 255;
    float v = (c < 32) ? Wf[k * 32 + c]
            : (c < 64) ? Wg[k * 32 + (c - 32)]
                       : Wh[k * 256 + (c - 64)];
    WT[c * 256 + k] = (_Float16)v;
}

// ---------- proj: one f16 MFMA GEMM, M=64/block, N=320, K=256 ------------------
// 4 waves: wave w -> rows 32*(w&1), n-tiles (w>>1)*5 .. +4 (tiles of 32 cols).
// Tiles 0,1 = f,g -> kf16/qf16; tiles 2..9 = h -> v_t (bf16, transposed via LDS).
__global__ __launch_bounds__(256) void proj_kernel(
    const float* __restrict__ x,
    const float* __restrict__ bfp, const float* __restrict__ bgp,
    const float* __restrict__ bhp,
    const _Float16* __restrict__ WT,
    _Float16* __restrict__ qf16, _Float16* __restrict__ kf16,
    unsigned short* __restrict__ v_t)
{
    __shared__ __align__(16) _Float16 xs[64 * 256];       // 32 KB, A-frag layout
    __shared__ __align__(16) unsigned short tbuf[4][32 * 40];  // per-wave xpose buf

    const int tid  = threadIdx.x;
    const int lane = tid & 63;
    const int wave = tid >> 6;
    const int m_   = lane & 31;
    const int k8   = lane >> 5;
    const int row0 = blockIdx.x * 64;
    const int b    = row0 >> 12;
    const int n0   = row0 & 4095;

    // phase A: load x (fp32), convert f16, store in MFMA-A layout
    #pragma unroll
    for (int i = 0; i < 8; i++) {
        int r  = 8 * i + (tid >> 5);
        int k0 = (tid & 31) * 8;
        const f32x4* src = (const f32x4*)(x + (size_t)(row0 + r) * 256 + k0);
        f32x4 a = src[0], c4 = src[1];
        f16x8 h = { (_Float16)a.x, (_Float16)a.y, (_Float16)a.z, (_Float16)a.w,
                    (_Float16)c4.x, (_Float16)c4.y, (_Float16)c4.z, (_Float16)c4.w };
        int unit = ((r >> 5) * 16 + (k0 >> 4)) * 64 + ((k0 >> 3) & 1) * 32 + (r & 31);
        *(f16x8*)(xs + unit * 8) = h;
    }
    __syncthreads();

    // phase B: GEMM
    const int rowsub = wave & 1;
    const int t0 = (wave >> 1) * 5;
    f32x16 acc[5];
    #pragma unroll
    for (int t = 0; t < 5; t++)
        #pragma unroll
        for (int i = 0; i < 16; i++) acc[t][i] = 0.f;

    #pragma unroll 2
    for (int ks = 0; ks < 16; ks++) {
        f16x8 A = *(const f16x8*)(xs + ((rowsub * 16 + ks) * 64 + lane) * 8);
        #pragma unroll
        for (int t = 0; t < 5; t++) {
            int cg = (t0 + t) * 32 + m_;
            f16x8 Bv = *(const f16x8*)(WT + cg * 256 + ks * 16 + k8 * 8);
            acc[t] = __builtin_amdgcn_mfma_f32_32x32x16_f16(A, Bv, acc[t], 0, 0, 0);
        }
    }

    // epilogue
    #pragma unroll
    for (int t = 0; t < 5; t++) {
        int tile = t0 + t;
        if (tile < 2) {            // f/g -> kf16/qf16 (waves 0,1 only)
            int col = tile * 32 + m_;
            float bias = (col < 32) ? bfp[col] : bgp[col - 32];
            _Float16* dst = (col < 32) ? kf16 : qf16;
            int cc = col & 31;
            #pragma unroll
            for (int r = 0; r < 16; r++) {
                int m = (r & 3) + 8 * (r >> 2) + 4 * k8;
                int row = row0 + rowsub * 32 + m;
                dst[(size_t)row * 32 + cc] = (_Float16)(acc[t][r] + bias);
            }
        } else {                   // h -> v_t[b][ch][n] bf16, transpose via LDS
            int ch = tile * 32 - 64 + m_;
            float bias = bhp[ch];
            unsigned short* buf = tbuf[wave];
            #pragma unroll
            for (int u = 0; u < 8; u++) {
                int r = 2 * u;
                int m = (r & 3) + 8 * (r >> 2) + 4 * k8;
                uint32_t v = (uint32_t)f2bf(acc[t][r] + bias)
                           | ((uint32_t)f2bf(acc[t][r + 1] + bias) << 16);
                *(uint32_t*)(buf + m_ * 40 + m) = v;
            }
            // same-wave write->read: lgkmcnt ordering suffices
            #pragma unroll
            for (int u = 0; u < 2; u++) {
                int idx2 = u * 64 + lane;
                int chr = idx2 >> 2, q8 = idx2 & 3;
                s16x8 vv = *(const s16x8*)(buf + chr * 40 + q8 * 8);
                int colh = (tile - 2) * 32 + chr;
                *(s16x8*)(v_t + ((size_t)(b * 256 + colh)) * 4096
                               + n0 + rowsub * 32 + q8 * 8) = vv;
            }
        }
    }
}

// ---------- flash attention v3: 32x32x16 MFMA, f16 scores, grid 512 -----------
// grid (128, 4): x = qt*2+chg (64 q-tiles x 2 ch-groups), y = batch.
// 4 waves: wave w -> q-rows 32*(w&1), channels 64*(w>>1) within the 128-ch group.
__global__ __launch_bounds__(256) void attn_kernel(
    const _Float16* __restrict__ qf16, const _Float16* __restrict__ kf16,
    const unsigned short* __restrict__ v_t,
    const float* __restrict__ x, const float* __restrict__ gamma_p,
    float* __restrict__ out)
{
    __shared__ __align__(16) _Float16 keys_s[2048];        // 64k x 32ck, 4 KB
    __shared__ __align__(16) unsigned short hT_s[8192];    // 128ch x 64k, 16 KB
    __shared__ __align__(16) unsigned short P_s[2][2048];  // per-qsub, 8 KB

    const int tid  = threadIdx.x;
    const int lane = tid & 63;
    const int wave = tid >> 6;
    const int qsub = wave & 1;
    const int csub = wave >> 1;
    const int m_   = lane & 31;
    const int k8   = lane >> 5;
    const int qt   = blockIdx.x >> 1;
    const int chg  = blockIdx.x & 1;
    const int b    = blockIdx.y;
    const size_t bn = (size_t)b * N_;
    const int ch0  = chg * 128;

    // Q A-fragments (f16), rows = queries (g)
    const int qrow = qt * 64 + qsub * 32 + m_;
    const f16x8 Aq0 = *(const f16x8*)(qf16 + (bn + qrow) * 32 + k8 * 8);
    const f16x8 Aq1 = *(const f16x8*)(qf16 + (bn + qrow) * 32 + 16 + k8 * 8);

    f32x16 acc0, acc1;
    float l_acc[16];
    #pragma unroll
    for (int i = 0; i < 16; i++) { acc0[i] = 0.f; acc1[i] = 0.f; l_acc[i] = 0.f; }

    // staging addresses (hoisted)
    const int skey = tid >> 2, skc = tid & 3;
    const int kunit = ((skc >> 1) * 2 + (skey >> 5)) * 64 + (skc & 1) * 32 + (skey & 31);

    for (int kt = 0; kt < N_ / 64; kt++) {
        // global loads first (overlap the barrier wait)
        f16x8 kv = *(const f16x8*)(kf16 + (bn + kt * 64 + skey) * 32 + skc * 8);
        s16x8 hv[4];
        #pragma unroll
        for (int rep = 0; rep < 4; rep++) {
            int idx = rep * 256 + tid;
            int i = idx >> 3, ko = idx & 7;
            hv[rep] = *(const s16x8*)(v_t + ((size_t)(b * 256 + ch0 + i)) * 4096
                                           + kt * 64 + ko * 8);
        }
        __syncthreads();   // previous tile's consumers done
        *(f16x8*)(keys_s + kunit * 8) = kv;
        #pragma unroll
        for (int rep = 0; rep < 4; rep++) {
            int idx = rep * 256 + tid;
            int i = idx >> 3, ko = idx & 7;
            int unit = (((i >> 5) * 4 + (ko >> 1)) * 2 + (ko & 1)) * 32 + (i & 31);
            *(s16x8*)(hT_s + unit * 8) = hv[rep];
        }
        __syncthreads();

        // S = Q K^T : 2 key-subtiles x 2 ksteps, f16 single pass
        f32x16 s0, s1;
        #pragma unroll
        for (int i = 0; i < 16; i++) { s0[i] = 0.f; s1[i] = 0.f; }
        s0 = __builtin_amdgcn_mfma_f32_32x32x16_f16(
                 Aq0, *(const f16x8*)(keys_s + ((0 * 2 + 0) * 64 + lane) * 8), s0, 0, 0, 0);
        s0 = __builtin_amdgcn_mfma_f32_32x32x16_f16(
                 Aq1, *(const f16x8*)(keys_s + ((1 * 2 + 0) * 64 + lane) * 8), s0, 0, 0, 0);
        s1 = __builtin_amdgcn_mfma_f32_32x32x16_f16(
                 Aq0, *(const f16x8*)(keys_s + ((0 * 2 + 1) * 64 + lane) * 8), s1, 0, 0, 0);
        s1 = __builtin_amdgcn_mfma_f32_32x32x16_f16(
                 Aq1, *(const f16x8*)(keys_s + ((1 * 2 + 1) * 64 + lane) * 8), s1, 0, 0, 0);

        // fixed-offset exp2 softmax numerator
        float p0[16], p1[16];
        #pragma unroll
        for (int r = 0; r < 16; r++) {
            p0[r] = __builtin_amdgcn_exp2f(fmaf(s0[r], LOG2E, -SOFT_OFF));
            p1[r] = __builtin_amdgcn_exp2f(fmaf(s1[r], LOG2E, -SOFT_OFF));
            l_acc[r] += p0[r] + p1[r];
        }

        // P writes (C-layout -> A-layout units), b32 packed via shfl.
        // waves 0&2 / 1&3 write identical values to the same buffer: benign.
        unsigned short* Pb = P_s[qsub];
        #pragma unroll
        for (int r = 0; r < 16; r++) {
            int m = (r & 3) + 8 * (r >> 2) + 4 * k8;
            uint32_t v0 = f2bf(p0[r]);
            uint32_t o0 = (uint32_t)__shfl_xor((int)v0, 1, 64);
            uint32_t v1 = f2bf(p1[r]);
            uint32_t o1 = (uint32_t)__shfl_xor((int)v1, 1, 64);
            if (!(lane & 1)) {
                int u0 = ((m_ >> 4) * 2 + ((m_ >> 3) & 1)) * 32 + m;        // keys 0-31
                int u1 = (((m_ >> 4) + 2) * 2 + ((m_ >> 3) & 1)) * 32 + m;  // keys 32-63
                *(uint32_t*)(Pb + u0 * 8 + (m_ & 6)) = v0 | (o0 << 16);
                *(uint32_t*)(Pb + u1 * 8 + (m_ & 6)) = v1 | (o1 << 16);
            }
        }
        // same-wave readback (own writes cover all bytes read): no barrier
        bf16x8 Ap[4];
        #pragma unroll
        for (int kstep = 0; kstep < 4; kstep++)
            Ap[kstep] = *(const bf16x8*)(Pb + ((kstep * 2 + k8) * 32 + m_) * 8);

        // O += P V over this wave's 2 channel tiles
        #pragma unroll
        for (int kstep = 0; kstep < 4; kstep++) {
            acc0 = __builtin_amdgcn_mfma_f32_32x32x16_bf16(
                Ap[kstep],
                *(const bf16x8*)(hT_s + (((csub * 2 + 0) * 4 + kstep) * 64 + lane) * 8),
                acc0, 0, 0, 0);
            acc1 = __builtin_amdgcn_mfma_f32_32x32x16_bf16(
                Ap[kstep],
                *(const bf16x8*)(hT_s + (((csub * 2 + 1) * 4 + kstep) * 64 + lane) * 8),
                acc1, 0, 0, 0);
        }
    }

    // epilogue: reduce l across the 32-lane col group, then y = gamma*O/l + x
    #pragma unroll
    for (int off = 1; off < 32; off <<= 1)
        #pragma unroll
        for (int r = 0; r < 16; r++)
            l_acc[r] += __shfl_xor(l_acc[r], off, 64);

    const float gamma = *gamma_p;
    #pragma unroll
    for (int r = 0; r < 16; r++) {
        int m = (r & 3) + 8 * (r >> 2) + 4 * k8;
        int row = qt * 64 + qsub * 32 + m;
        float rcp = 1.0f / l_acc[r];
        size_t base = (bn + row) * 256 + ch0 + csub * 64 + m_;
        out[base]      = gamma * (acc0[r] * rcp) + x[base];
        out[base + 32] = gamma * (acc1[r] * rcp) + x[base + 32];
    }
}

extern "C" void kernel_launch(void* const* d_in, const int* in_sizes, int n_in,
                              void* d_out, int out_size, void* d_ws, size_t ws_size,
                              hipStream_t stream) {
    const float* x   = (const float*)d_in[0];
    const float* Wf  = (const float*)d_in[1];
    const float* bfp = (const float*)d_in[2];
    const float* Wg  = (const float*)d_in[3];
    const float* bgp = (const float*)d_in[4];
    const float* Wh  = (const float*)d_in[5];
    const float* bhp = (const float*)d_in[6];
    const float* gam = (const float*)d_in[7];
    float* out = (float*)d_out;

    unsigned char* ws = (unsigned char*)d_ws;
    const size_t MB = 1 << 20;
    _Float16* WT    = (_Float16*)(ws);              // [320][256] f16, 160 KB
    _Float16* qf16  = (_Float16*)(ws + 1 * MB);     // [B*N][32] f16 (queries g)
    _Float16* kf16  = (_Float16*)(ws + 2 * MB);     // [B*N][32] f16 (keys f)
    unsigned short* v_t = (unsigned short*)(ws + 3 * MB);  // [B][C][N] bf16, 8 MB

    wprep<<<dim3(320), dim3(256), 0, stream>>>(Wf, Wg, Wh, WT);
    proj_kernel<<<dim3(B_ * N_ / 64), dim3(256), 0, stream>>>(
        x, bfp, bgp, bhp, WT, qf16, kf16, v_t);
    attn_kernel<<<dim3(128, B_), dim3(256), 0, stream>>>(
        qf16, kf16, v_t, x, gam, out);
}

// Round 4
// 231.703 us; speedup vs baseline: 1.4474x; 1.3098x over previous
//
#include <hip/hip_runtime.h>
#include <stdint.h>

#define B_ 4
#define N_ 4096
#define C_ 256
#define LOG2E 1.44269504088896340736f
#define SOFT_OFF 88.0f

typedef float f32x4 __attribute__((ext_vector_type(4)));
typedef float f32x16 __attribute__((ext_vector_type(16)));
typedef short s16x8 __attribute__((ext_vector_type(8)));
typedef __bf16 bf16x8 __attribute__((ext_vector_type(8)));
typedef _Float16 f16x8 __attribute__((ext_vector_type(8)));

static __device__ __forceinline__ unsigned short f2bf(float f) {
    union { float f; uint32_t u; } v; v.f = f;
    return (unsigned short)((v.u + 0x7FFFu + ((v.u >> 16) & 1u)) >> 16);
}

// ---------- wprep v2: coalesced LDS transpose, W -> WT f16 [320][256] ----------
// grid (10 col-tiles, 4 k-chunks). tile 0 = Wf, 1 = Wg, 2-9 = Wh cols (t-2)*32.
__global__ __launch_bounds__(256) void wprep(
    const float* __restrict__ Wf, const float* __restrict__ Wg,
    const float* __restrict__ Wh, _Float16* __restrict__ WT)
{
    __shared__ float tile[64][33];
    const int t = blockIdx.x, kc = blockIdx.y, tid = threadIdx.x;
    const float* src; int stride;
    if (t == 0)      { src = Wf;              stride = 32;  }
    else if (t == 1) { src = Wg;              stride = 32;  }
    else             { src = Wh + (t - 2) * 32; stride = 256; }

    const int c = tid & 31, a = tid >> 5;
    #pragma unroll
    for (int p = 0; p < 8; p++) {
        int kk = p * 8 + a;
        tile[kk][c] = src[(size_t)(kc * 64 + kk) * stride + c];
    }
    __syncthreads();
    const int kk = tid & 63, aa = tid >> 6;
    #pragma unroll
    for (int p = 0; p < 8; p++) {
        int cc = p * 4 + aa;
        WT[(size_t)(t * 32 + cc) * 256 + kc * 64 + kk] = (_Float16)tile[kk][cc];
    }
}

// ---------- proj: f16 MFMA GEMM, M=64/block, tiles split across gridDim.y ------
// grid (256, 2): y=0 -> tiles 0-5 (f,g,h0-h3), y=1 -> tiles 6-9 (h4-h7).
// 4 waves: rowsub = wave&1 (32 rows), tg = wave>>1 (3 or 2 tiles of 32 cols).
__global__ __launch_bounds__(256, 2) void proj_kernel(
    const float* __restrict__ x,
    const float* __restrict__ bfp, const float* __restrict__ bgp,
    const float* __restrict__ bhp,
    const _Float16* __restrict__ WT,
    _Float16* __restrict__ qf16, _Float16* __restrict__ kf16,
    unsigned short* __restrict__ v_t)
{
    __shared__ __align__(16) _Float16 xs[64 * 256];            // 32 KB, swizzled
    __shared__ __align__(16) unsigned short tbuf[4][32 * 40];  // per-wave xpose

    const int tid  = threadIdx.x;
    const int lane = tid & 63;
    const int wave = tid >> 6;
    const int m_   = lane & 31;
    const int k8   = lane >> 5;
    const int row0 = blockIdx.x * 64;
    const int half = blockIdx.y;
    const int b    = row0 >> 12;
    const int n0   = row0 & 4095;

    // stage x -> f16 in swizzled MFMA-A layout (conflict-free write & read)
    #pragma unroll
    for (int i = 0; i < 8; i++) {
        int r  = 8 * i + (tid >> 5);
        int c5 = tid & 31;
        const f32x4* src = (const f32x4*)(x + (size_t)(row0 + r) * 256 + c5 * 8);
        f32x4 a = src[0], c4 = src[1];
        f16x8 h = { (_Float16)a.x, (_Float16)a.y, (_Float16)a.z, (_Float16)a.w,
                    (_Float16)c4.x, (_Float16)c4.y, (_Float16)c4.z, (_Float16)c4.w };
        int chunk = (((r >> 5) * 16 + (c5 >> 1)) * 2 + (c5 & 1)) * 32
                  + ((r & 31) ^ (c5 & 7));
        *(f16x8*)(xs + chunk * 8) = h;
    }
    __syncthreads();

    const int rowsub = wave & 1;
    const int tg     = wave >> 1;
    const int ntile  = (half == 0) ? 3 : 2;
    const int t_base = (half == 0) ? tg * 3 : 6 + tg * 2;

    f32x16 acc[3];
    #pragma unroll
    for (int t = 0; t < 3; t++)
        #pragma unroll
        for (int i = 0; i < 16; i++) acc[t][i] = 0.f;

    #pragma unroll 2
    for (int ks = 0; ks < 16; ks++) {
        f16x8 A = *(const f16x8*)(xs + ((((rowsub * 16 + ks) * 2 + k8) * 32)
                                        + (m_ ^ ((ks * 2 + k8) & 7))) * 8);
        #pragma unroll
        for (int t = 0; t < 3; t++) {
            if (t >= ntile) break;
            int cg = (t_base + t) * 32 + m_;
            f16x8 Bv = *(const f16x8*)(WT + (size_t)cg * 256 + ks * 16 + k8 * 8);
            acc[t] = __builtin_amdgcn_mfma_f32_32x32x16_f16(A, Bv, acc[t], 0, 0, 0);
        }
    }

    #pragma unroll
    for (int t = 0; t < 3; t++) {
        if (t >= ntile) break;
        int tile = t_base + t;
        if (tile < 2) {            // f -> kf16, g -> qf16
            float bias = (tile == 0) ? bfp[m_] : bgp[m_];
            _Float16* dst = (tile == 0) ? kf16 : qf16;
            #pragma unroll
            for (int r = 0; r < 16; r++) {
                int m = (r & 3) + 8 * (r >> 2) + 4 * k8;
                int row = row0 + rowsub * 32 + m;
                dst[(size_t)row * 32 + m_] = (_Float16)(acc[t][r] + bias);
            }
        } else {                   // h -> v_t[b][ch][n] bf16 via LDS transpose
            int ch = (tile - 2) * 32 + m_;
            float bias = bhp[ch];
            unsigned short* buf = tbuf[wave];
            #pragma unroll
            for (int u = 0; u < 8; u++) {
                int r = 2 * u;
                int m = (r & 3) + 8 * (r >> 2) + 4 * k8;
                uint32_t v = (uint32_t)f2bf(acc[t][r] + bias)
                           | ((uint32_t)f2bf(acc[t][r + 1] + bias) << 16);
                *(uint32_t*)(buf + m_ * 40 + m) = v;
            }
            #pragma unroll
            for (int u = 0; u < 2; u++) {
                int idx2 = u * 64 + lane;
                int chr = idx2 >> 2, q8 = idx2 & 3;
                s16x8 vv = *(const s16x8*)(buf + chr * 40 + q8 * 8);
                int colh = (tile - 2) * 32 + chr;
                *(s16x8*)(v_t + ((size_t)(b * 256 + colh)) * 4096
                               + n0 + rowsub * 32 + q8 * 8) = vv;
            }
        }
    }
}

// ---------- flash attention v4: key-split waves, swizzled LDS, 1024 blocks ----
// grid (64 qt, 4 chg, 4 b), 256 thr = 2 qsub x 2 csub waves.
// Wave (qsub,csub): S for (32q, keys csub*32..+31) -> P_s[qsub]; barrier;
// PV for (32q, ch chg*64 + csub*32 ..+31) over all 64 keys.
__global__ __launch_bounds__(256, 4) void attn_kernel(
    const _Float16* __restrict__ qf16, const _Float16* __restrict__ kf16,
    const unsigned short* __restrict__ v_t,
    const float* __restrict__ x, const float* __restrict__ gamma_p,
    float* __restrict__ out)
{
    __shared__ __align__(16) _Float16 keys_s[2048];        // 4 KB  (swizzled)
    __shared__ __align__(16) unsigned short hT_s[4096];    // 8 KB  (swizzled)
    __shared__ __align__(16) unsigned short P_s[2][2048];  // 8 KB  (swizzled)
    __shared__ float l_s[2][2][2][16];                     // qsub,csub,k8,r

    const int tid  = threadIdx.x;
    const int lane = tid & 63;
    const int wave = tid >> 6;
    const int qsub = wave & 1;
    const int csub = wave >> 1;
    const int m_   = lane & 31;
    const int k8   = lane >> 5;
    const int qt   = blockIdx.x;
    const int chg  = blockIdx.y;
    const int b    = blockIdx.z;
    const size_t bn = (size_t)b * N_;
    const int ch0  = chg * 64;

    // Q A-fragments
    const int qrow = qt * 64 + qsub * 32 + m_;
    const f16x8 Aq0 = *(const f16x8*)(qf16 + (bn + qrow) * 32 + k8 * 8);
    const f16x8 Aq1 = *(const f16x8*)(qf16 + (bn + qrow) * 32 + 16 + k8 * 8);

    f32x16 acc;
    float l_acc[16];
    #pragma unroll
    for (int i = 0; i < 16; i++) { acc[i] = 0.f; l_acc[i] = 0.f; }

    // staging index precompute (conflict-free by XOR swizzle)
    const int skey = tid >> 2, skc = tid & 3;
    const int kchunk = (((skc >> 1) * 2 + (skey >> 5)) * 2 + (skc & 1)) * 32
                     + ((skey & 31) ^ skc);
    const int hko = tid & 7, hi = tid >> 3;          // ko 0-7, ch 0-31 (+32 rep1)
    const int hchunk0 = hko * 32 + (hi ^ hko);       // rep1: +256
    const int ko2w = csub * 4 + (m_ >> 3);           // P-write key octet

    for (int kt = 0; kt < N_ / 64; kt++) {
        // global prefetch before barrier
        f16x8 kv = *(const f16x8*)(kf16 + (bn + kt * 64 + skey) * 32 + skc * 8);
        s16x8 hv0 = *(const s16x8*)(v_t + ((size_t)(b * 256 + ch0 + hi)) * 4096
                                         + kt * 64 + hko * 8);
        s16x8 hv1 = *(const s16x8*)(v_t + ((size_t)(b * 256 + ch0 + 32 + hi)) * 4096
                                         + kt * 64 + hko * 8);
        __syncthreads();   // prev tile's consumers done
        *(f16x8*)(keys_s + kchunk * 8) = kv;
        *(s16x8*)(hT_s + hchunk0 * 8) = hv0;
        *(s16x8*)(hT_s + (hchunk0 + 256) * 8) = hv1;
        __syncthreads();

        // S for this wave's 32-key half (f16 single pass, K=32)
        f32x16 s;
        #pragma unroll
        for (int i = 0; i < 16; i++) s[i] = 0.f;
        f16x8 Bk0 = *(const f16x8*)(keys_s + ((csub * 2 + k8) * 32 + (m_ ^ k8)) * 8);
        f16x8 Bk1 = *(const f16x8*)(keys_s + (((2 + csub) * 2 + k8) * 32
                                              + (m_ ^ (2 + k8))) * 8);
        s = __builtin_amdgcn_mfma_f32_32x32x16_f16(Aq0, Bk0, s, 0, 0, 0);
        s = __builtin_amdgcn_mfma_f32_32x32x16_f16(Aq1, Bk1, s, 0, 0, 0);

        // fixed-offset exp2 softmax numerator
        float p[16];
        #pragma unroll
        for (int r = 0; r < 16; r++) {
            p[r] = __builtin_amdgcn_exp2f(fmaf(s[r], LOG2E, -SOFT_OFF));
            l_acc[r] += p[r];
        }

        // P write: C-layout -> swizzled A-layout chunks, b32 packed via shfl
        unsigned short* Pb = P_s[qsub];
        #pragma unroll
        for (int r = 0; r < 16; r++) {
            int m = (r & 3) + 8 * (r >> 2) + 4 * k8;
            uint32_t v = f2bf(p[r]);
            uint32_t o = (uint32_t)__shfl_xor((int)v, 1, 64);
            if (!(lane & 1))
                *(uint32_t*)(Pb + (ko2w * 32 + (m ^ (ko2w & 3))) * 8 + (m_ & 6))
                    = v | (o << 16);
        }
        __syncthreads();   // P from both csub waves visible

        // PV: 4 ksteps over 64 keys, this wave's 32 channels
        #pragma unroll
        for (int kstep = 0; kstep < 4; kstep++) {
            int ko2 = kstep * 2 + k8;
            bf16x8 Ap = *(const bf16x8*)(Pb + (ko2 * 32 + (m_ ^ (ko2 & 3))) * 8);
            bf16x8 Bv = *(const bf16x8*)(hT_s + ((csub * 8 + ko2) * 32
                                                 + (m_ ^ ko2)) * 8);
            acc = __builtin_amdgcn_mfma_f32_32x32x16_bf16(Ap, Bv, acc, 0, 0, 0);
        }
    }

    // l: reduce over this wave's 32 key-cols, then combine csub partners
    #pragma unroll
    for (int off = 1; off < 32; off <<= 1)
        #pragma unroll
        for (int r = 0; r < 16; r++)
            l_acc[r] += __shfl_xor(l_acc[r], off, 64);
    if (m_ == 0)
        #pragma unroll
        for (int r = 0; r < 16; r++)
            l_s[qsub][csub][k8][r] = l_acc[r];
    __syncthreads();

    const float gamma = *gamma_p;
    #pragma unroll
    for (int r = 0; r < 16; r++) {
        float ltot = l_acc[r] + l_s[qsub][csub ^ 1][k8][r];
        float rcp = 1.0f / ltot;
        int m = (r & 3) + 8 * (r >> 2) + 4 * k8;
        int row = qt * 64 + qsub * 32 + m;
        size_t idx = (bn + row) * 256 + ch0 + csub * 32 + m_;
        out[idx] = gamma * (acc[r] * rcp) + x[idx];
    }
}

extern "C" void kernel_launch(void* const* d_in, const int* in_sizes, int n_in,
                              void* d_out, int out_size, void* d_ws, size_t ws_size,
                              hipStream_t stream) {
    const float* x   = (const float*)d_in[0];
    const float* Wf  = (const float*)d_in[1];
    const float* bfp = (const float*)d_in[2];
    const float* Wg  = (const float*)d_in[3];
    const float* bgp = (const float*)d_in[4];
    const float* Wh  = (const float*)d_in[5];
    const float* bhp = (const float*)d_in[6];
    const float* gam = (const float*)d_in[7];
    float* out = (float*)d_out;

    unsigned char* ws = (unsigned char*)d_ws;
    const size_t MB = 1 << 20;
    _Float16* WT    = (_Float16*)(ws);              // [320][256] f16, 160 KB
    _Float16* qf16  = (_Float16*)(ws + 1 * MB);     // [B*N][32] f16 (queries g)
    _Float16* kf16  = (_Float16*)(ws + 2 * MB);     // [B*N][32] f16 (keys f)
    unsigned short* v_t = (unsigned short*)(ws + 3 * MB);  // [B][C][N] bf16, 8 MB

    wprep<<<dim3(10, 4), dim3(256), 0, stream>>>(Wf, Wg, Wh, WT);
    proj_kernel<<<dim3(256, 2), dim3(256), 0, stream>>>(
        x, bfp, bgp, bhp, WT, qf16, kf16, v_t);
    attn_kernel<<<dim3(64, 4, 4), dim3(256), 0, stream>>>(
        qf16, kf16, v_t, x, gam, out);
}

// Round 5
// 164.883 us; speedup vs baseline: 2.0340x; 1.4053x over previous
//
#include <hip/hip_runtime.h>
#include <stdint.h>

#define B_ 4
#define N_ 4096
#define C_ 256
#define LOG2E 1.44269504088896340736f
#define SOFT_OFF 88.0f

typedef float f32x4 __attribute__((ext_vector_type(4)));
typedef float f32x16 __attribute__((ext_vector_type(16)));
typedef short s16x8 __attribute__((ext_vector_type(8)));
typedef __bf16 bf16x8 __attribute__((ext_vector_type(8)));
typedef _Float16 f16x8 __attribute__((ext_vector_type(8)));

static __device__ __forceinline__ unsigned short f2bf(float f) {
    union { float f; uint32_t u; } v; v.f = f;
    return (unsigned short)((v.u + 0x7FFFu + ((v.u >> 16) & 1u)) >> 16);
}
static __device__ __forceinline__ unsigned short f2bf_rh(float f) {
    union { float f; uint32_t u; } v; v.f = f;   // round-half-up: 2 VALU ops
    return (unsigned short)((v.u + 0x8000u) >> 16);
}

// ---------- wprep: coalesced LDS transpose, W -> WT f16 [320][256] ----------
__global__ __launch_bounds__(256) void wprep(
    const float* __restrict__ Wf, const float* __restrict__ Wg,
    const float* __restrict__ Wh, _Float16* __restrict__ WT)
{
    __shared__ float tile[64][33];
    const int t = blockIdx.x, kc = blockIdx.y, tid = threadIdx.x;
    const float* src; int stride;
    if (t == 0)      { src = Wf;                stride = 32;  }
    else if (t == 1) { src = Wg;                stride = 32;  }
    else             { src = Wh + (t - 2) * 32; stride = 256; }

    const int c = tid & 31, a = tid >> 5;
    #pragma unroll
    for (int p = 0; p < 8; p++) {
        int kk = p * 8 + a;
        tile[kk][c] = src[(size_t)(kc * 64 + kk) * stride + c];
    }
    __syncthreads();
    const int kk = tid & 63, aa = tid >> 6;
    #pragma unroll
    for (int p = 0; p < 8; p++) {
        int cc = p * 4 + aa;
        WT[(size_t)(t * 32 + cc) * 256 + kc * 64 + kk] = (_Float16)tile[kk][cc];
    }
}

// ---------- proj v5: f16 MFMA GEMM with LDS-staged double-buffered WT ----------
// grid (256, 2): y=0 -> tiles 0-5 (f,g,h0-h3), y=1 -> tiles 6-9 (h4-h7).
// 4 waves: rowsub = wave&1, tg = wave>>1 (3 or 2 tiles of 32 cols).
__global__ __launch_bounds__(256, 3) void proj_kernel(
    const float* __restrict__ x,
    const float* __restrict__ bfp, const float* __restrict__ bgp,
    const float* __restrict__ bhp,
    const _Float16* __restrict__ WT,
    _Float16* __restrict__ qf16, _Float16* __restrict__ kf16,
    unsigned short* __restrict__ v_t)
{
    // pool: xs 32KB | wshare 12KB (wts dbuf during loop, tbuf in epilogue)
    __shared__ __align__(16) unsigned short pool[16384 + 6144];
    _Float16* xs = (_Float16*)pool;                       // 64x256 f16
    _Float16* wts[2] = { (_Float16*)(pool + 16384),       // [k8][192 pair][8]
                         (_Float16*)(pool + 16384 + 3072) };
    unsigned short* tbuf = pool + 16384;                  // epilogue overlay

    const int tid  = threadIdx.x;
    const int lane = tid & 63;
    const int wave = tid >> 6;
    const int m_   = lane & 31;
    const int k8   = lane >> 5;
    const int row0 = blockIdx.x * 64;
    const int half = blockIdx.y;
    const int b    = row0 >> 12;
    const int n0   = row0 & 4095;
    const int npair = half ? 128 : 192;

    // stage x -> f16, swizzled MFMA-A layout
    #pragma unroll
    for (int i = 0; i < 8; i++) {
        int r  = 8 * i + (tid >> 5);
        int c5 = tid & 31;
        const f32x4* src = (const f32x4*)(x + (size_t)(row0 + r) * 256 + c5 * 8);
        f32x4 a = src[0], c4 = src[1];
        f16x8 h = { (_Float16)a.x, (_Float16)a.y, (_Float16)a.z, (_Float16)a.w,
                    (_Float16)c4.x, (_Float16)c4.y, (_Float16)c4.z, (_Float16)c4.w };
        int chunk = (((r >> 5) * 16 + (c5 >> 1)) * 2 + (c5 & 1)) * 32
                  + ((r & 31) ^ (c5 & 7));
        *(f16x8*)(xs + chunk * 8) = h;
    }
    // stage WT slice for ks=0
    if (tid < npair) {
        const _Float16* s = WT + (size_t)(half * 192 + tid) * 256;
        f16x8 w0 = *(const f16x8*)(s), w1 = *(const f16x8*)(s + 8);
        *(f16x8*)(wts[0] + (0 * 192 + tid) * 8) = w0;
        *(f16x8*)(wts[0] + (1 * 192 + tid) * 8) = w1;
    }
    __syncthreads();

    const int rowsub = wave & 1;
    const int tg     = wave >> 1;
    const int ntile  = (half == 0) ? 3 : 2;
    const int lt0    = (half == 0) ? tg * 3 : tg * 2;   // local tile base in slice
    const int t_base = (half == 0) ? tg * 3 : 6 + tg * 2;

    f32x16 acc[3];
    #pragma unroll
    for (int t = 0; t < 3; t++)
        #pragma unroll
        for (int i = 0; i < 16; i++) acc[t][i] = 0.f;

    for (int ks = 0; ks < 16; ks++) {
        const int cur = ks & 1, nxt = cur ^ 1;
        const int ksn = (ks < 15) ? ks + 1 : 15;
        // prefetch next WT slice into regs
        f16x8 w0, w1;
        if (tid < npair) {
            const _Float16* s = WT + (size_t)(half * 192 + tid) * 256 + ksn * 16;
            w0 = *(const f16x8*)(s); w1 = *(const f16x8*)(s + 8);
        }
        // compute on current slice
        f16x8 A = *(const f16x8*)(xs + ((((rowsub * 16 + ks) * 2 + k8) * 32)
                                        + (m_ ^ ((ks * 2 + k8) & 7))) * 8);
        #pragma unroll
        for (int t = 0; t < 3; t++) {
            if (t >= ntile) break;
            f16x8 Bv = *(const f16x8*)(wts[cur] + (k8 * 192 + (lt0 + t) * 32 + m_) * 8);
            acc[t] = __builtin_amdgcn_mfma_f32_32x32x16_f16(A, Bv, acc[t], 0, 0, 0);
        }
        __syncthreads();                      // readers of wts[nxt] (ks-1) done
        if (tid < npair) {
            *(f16x8*)(wts[nxt] + (0 * 192 + tid) * 8) = w0;
            *(f16x8*)(wts[nxt] + (1 * 192 + tid) * 8) = w1;
        }
        __syncthreads();                      // wts[nxt] visible for ks+1
    }

    // epilogue (tbuf overlays wts; all compute reads completed at last barrier)
    #pragma unroll
    for (int t = 0; t < 3; t++) {
        if (t >= ntile) break;
        int tile = t_base + t;
        if (tile < 2) {            // f -> kf16, g -> qf16
            float bias = (tile == 0) ? bfp[m_] : bgp[m_];
            _Float16* dst = (tile == 0) ? kf16 : qf16;
            #pragma unroll
            for (int r = 0; r < 16; r++) {
                int m = (r & 3) + 8 * (r >> 2) + 4 * k8;
                int row = row0 + rowsub * 32 + m;
                dst[(size_t)row * 32 + m_] = (_Float16)(acc[t][r] + bias);
            }
        } else {                   // h -> v_t[b][ch][n] bf16 via LDS transpose
            int ch = (tile - 2) * 32 + m_;
            float bias = bhp[ch];
            unsigned short* buf = tbuf + wave * (32 * 40);
            #pragma unroll
            for (int u = 0; u < 8; u++) {
                int r = 2 * u;
                int m = (r & 3) + 8 * (r >> 2) + 4 * k8;
                uint32_t v = (uint32_t)f2bf(acc[t][r] + bias)
                           | ((uint32_t)f2bf(acc[t][r + 1] + bias) << 16);
                *(uint32_t*)(buf + m_ * 40 + m) = v;
            }
            #pragma unroll
            for (int u = 0; u < 2; u++) {
                int idx2 = u * 64 + lane;
                int chr = idx2 >> 2, q8 = idx2 & 3;
                s16x8 vv = *(const s16x8*)(buf + chr * 40 + q8 * 8);
                int colh = (tile - 2) * 32 + chr;
                *(s16x8*)(v_t + ((size_t)(b * 256 + colh)) * 4096
                               + n0 + rowsub * 32 + q8 * 8) = vv;
            }
        }
    }
}

// ---------- flash attention v5: pipelined dbuf, reg-prefetched K, b16 P -------
// grid (64 qt, 2 chg, 4 b) = 512 blocks, 512 thr = 8 waves.
// S-duty (waves 0-3): qsub = w&1, ksub = w>>1 -> S(32q x 32keys), P -> LDS.
// PV (all 8): qsub = w&1, chsl = w>>1 -> O(32q x 32ch) over 64 keys.
__global__ __launch_bounds__(512, 4) void attn_kernel(
    const _Float16* __restrict__ qf16, const _Float16* __restrict__ kf16,
    const unsigned short* __restrict__ v_t,
    const float* __restrict__ x, const float* __restrict__ gamma_p,
    float* __restrict__ out)
{
    __shared__ __align__(16) unsigned short hT_s[2][8192];  // [buf][oct][ch^oct][8]
    __shared__ __align__(16) unsigned short P_s[2][2048];   // [qsub][oct][q^swz][8]
    __shared__ float l_s[2][2][32];                         // [qsub][ksub][q]

    const int tid  = threadIdx.x;
    const int lane = tid & 63;
    const int wave = tid >> 6;
    const int qsub = wave & 1;
    const int chsl = wave >> 1;       // PV channel slice (0..3); == ksub for w<4
    const int m_   = lane & 31;
    const int k8   = lane >> 5;
    const int qt   = blockIdx.x;
    const int chg  = blockIdx.y;
    const int b    = blockIdx.z;
    const size_t bn = (size_t)b * N_;
    const int ch0  = chg * 128;
    const bool is_s = (wave < 4);
    const int ksub  = wave >> 1;      // valid for S-waves

    // hT staging map: thread -> (ch = hi0 / 64+hi0, key-octet hko)
    const int hi0 = tid >> 3;
    const int hko = tid & 7;
    const size_t hrow0 = ((size_t)(b * 256 + ch0 + hi0)) * 4096 + hko * 8;
    const size_t hrow1 = ((size_t)(b * 256 + ch0 + 64 + hi0)) * 4096 + hko * 8;
    const int hc0 = (hko * 128 + (hi0 ^ hko)) * 8;
    const int hc1 = (hko * 128 + ((64 + hi0) ^ hko)) * 8;

    // Q A-fragments (S-waves)
    f16x8 Aq0, Aq1, Kc0, Kc1;
    if (is_s) {
        const int qrow = qt * 64 + qsub * 32 + m_;
        Aq0 = *(const f16x8*)(qf16 + (bn + qrow) * 32 + k8 * 8);
        Aq1 = *(const f16x8*)(qf16 + (bn + qrow) * 32 + 16 + k8 * 8);
        const _Float16* kp = kf16 + (bn + ksub * 32 + m_) * 32;
        Kc0 = *(const f16x8*)(kp + k8 * 8);
        Kc1 = *(const f16x8*)(kp + 16 + k8 * 8);
    }

    // prologue: stage hT tile 0
    {
        s16x8 h0 = *(const s16x8*)(v_t + hrow0);
        s16x8 h1 = *(const s16x8*)(v_t + hrow1);
        *(s16x8*)(&hT_s[0][hc0]) = h0;
        *(s16x8*)(&hT_s[0][hc1]) = h1;
    }
    __syncthreads();

    f32x16 acc;
    float l_acc[16];
    #pragma unroll
    for (int i = 0; i < 16; i++) { acc[i] = 0.f; l_acc[i] = 0.f; }

    for (int kt = 0; kt < N_ / 64; kt++) {
        const int cur = kt & 1, nxt = cur ^ 1;
        const int ktn = (kt < 63) ? kt + 1 : 63;
        // prefetch next tile (global -> regs)
        s16x8 h0 = *(const s16x8*)(v_t + (size_t)ktn * 64 + hrow0);
        s16x8 h1 = *(const s16x8*)(v_t + (size_t)ktn * 64 + hrow1);
        f16x8 Kn0, Kn1;
        if (is_s) {
            const _Float16* kp = kf16 + (bn + ktn * 64 + ksub * 32 + m_) * 32;
            Kn0 = *(const f16x8*)(kp + k8 * 8);
            Kn1 = *(const f16x8*)(kp + 16 + k8 * 8);
        }
        if (is_s) {
            // S = Q K^T for this wave's 32-key half (K-frags in regs)
            f32x16 s;
            #pragma unroll
            for (int i = 0; i < 16; i++) s[i] = 0.f;
            s = __builtin_amdgcn_mfma_f32_32x32x16_f16(Aq0, Kc0, s, 0, 0, 0);
            s = __builtin_amdgcn_mfma_f32_32x32x16_f16(Aq1, Kc1, s, 0, 0, 0);
            // fixed-offset exp2 softmax numerator; P -> LDS (16 b16, 2-way max)
            unsigned short* Pb = P_s[qsub];
            const int octet = ksub * 4 + (m_ >> 3);
            const int kofs = m_ & 7;
            #pragma unroll
            for (int r = 0; r < 16; r++) {
                float p = __builtin_amdgcn_exp2f(fmaf(s[r], LOG2E, -SOFT_OFF));
                l_acc[r] += p;
                int m = (r & 3) + 8 * (r >> 2) + 4 * k8;
                Pb[(octet * 32 + (m ^ (octet & 3))) * 8 + kofs] = f2bf_rh(p);
            }
        }
        __syncthreads();   // b1: P visible; hT[cur] still valid

        // PV: O += P V for (qsub, chsl), 4 ksteps over 64 keys
        const unsigned short* Pr = P_s[qsub];
        const unsigned short* Hc = hT_s[cur];
        #pragma unroll
        for (int kstep = 0; kstep < 4; kstep++) {
            int oct = kstep * 2 + k8;
            bf16x8 Ap = *(const bf16x8*)(Pr + (oct * 32 + (m_ ^ (oct & 3))) * 8);
            bf16x8 Bv = *(const bf16x8*)(Hc + (oct * 128 + ((chsl * 32 + m_) ^ oct)) * 8);
            acc = __builtin_amdgcn_mfma_f32_32x32x16_bf16(Ap, Bv, acc, 0, 0, 0);
        }
        // stage next hT tile
        *(s16x8*)(&hT_s[nxt][hc0]) = h0;
        *(s16x8*)(&hT_s[nxt][hc1]) = h1;
        if (is_s) { Kc0 = Kn0; Kc1 = Kn1; }
        __syncthreads();   // b2: hT[nxt] visible; P readers done
    }

    // l: reduce over 32 key-lanes (xor<32 stays within k8 half), publish, combine
    if (is_s) {
        #pragma unroll
        for (int off = 1; off < 32; off <<= 1)
            #pragma unroll
            for (int r = 0; r < 16; r++)
                l_acc[r] += __shfl_xor(l_acc[r], off, 64);
        if (m_ == 0) {
            #pragma unroll
            for (int r = 0; r < 16; r++) {
                int q = (r & 3) + 8 * (r >> 2) + 4 * k8;
                l_s[qsub][ksub][q] = l_acc[r];
            }
        }
    }
    __syncthreads();

    const float gamma = *gamma_p;
    #pragma unroll
    for (int r = 0; r < 16; r++) {
        int q = (r & 3) + 8 * (r >> 2) + 4 * k8;
        float l = l_s[qsub][0][q] + l_s[qsub][1][q];
        size_t idx = (bn + qt * 64 + qsub * 32 + q) * 256 + ch0 + chsl * 32 + m_;
        out[idx] = gamma * (acc[r] / l) + x[idx];
    }
}

extern "C" void kernel_launch(void* const* d_in, const int* in_sizes, int n_in,
                              void* d_out, int out_size, void* d_ws, size_t ws_size,
                              hipStream_t stream) {
    const float* x   = (const float*)d_in[0];
    const float* Wf  = (const float*)d_in[1];
    const float* bfp = (const float*)d_in[2];
    const float* Wg  = (const float*)d_in[3];
    const float* bgp = (const float*)d_in[4];
    const float* Wh  = (const float*)d_in[5];
    const float* bhp = (const float*)d_in[6];
    const float* gam = (const float*)d_in[7];
    float* out = (float*)d_out;

    unsigned char* ws = (unsigned char*)d_ws;
    const size_t MB = 1 << 20;
    _Float16* WT    = (_Float16*)(ws);              // [320][256] f16, 160 KB
    _Float16* qf16  = (_Float16*)(ws + 1 * MB);     // [B*N][32] f16 (queries g)
    _Float16* kf16  = (_Float16*)(ws + 2 * MB);     // [B*N][32] f16 (keys f)
    unsigned short* v_t = (unsigned short*)(ws + 3 * MB);  // [B][C][N] bf16, 8 MB

    wprep<<<dim3(10, 4), dim3(256), 0, stream>>>(Wf, Wg, Wh, WT);
    proj_kernel<<<dim3(256, 2), dim3(256), 0, stream>>>(
        x, bfp, bgp, bhp, WT, qf16, kf16, v_t);
    attn_kernel<<<dim3(64, 2, 4), dim3(512), 0, stream>>>(
        qf16, kf16, v_t, x, gam, out);
}

// Round 6
// 158.681 us; speedup vs baseline: 2.1135x; 1.0391x over previous
//
#include <hip/hip_runtime.h>
#include <stdint.h>

#define B_ 4
#define N_ 4096
#define C_ 256
#define LOG2E 1.44269504088896340736f
#define SOFT_OFF 88.0f

typedef float f32x4 __attribute__((ext_vector_type(4)));
typedef float f32x16 __attribute__((ext_vector_type(16)));
typedef short s16x8 __attribute__((ext_vector_type(8)));
typedef __bf16 bf16x8 __attribute__((ext_vector_type(8)));
typedef _Float16 f16x8 __attribute__((ext_vector_type(8)));

static __device__ __forceinline__ unsigned short f2bf(float f) {
    union { float f; uint32_t u; } v; v.f = f;
    return (unsigned short)((v.u + 0x7FFFu + ((v.u >> 16) & 1u)) >> 16);
}
static __device__ __forceinline__ unsigned short f2bf_rh(float f) {
    union { float f; uint32_t u; } v; v.f = f;
    return (unsigned short)((v.u + 0x8000u) >> 16);
}

// ---------- wprep: coalesced LDS transpose, W -> WT f16 [320][256] ----------
__global__ __launch_bounds__(256) void wprep(
    const float* __restrict__ Wf, const float* __restrict__ Wg,
    const float* __restrict__ Wh, _Float16* __restrict__ WT)
{
    __shared__ float tile[64][33];
    const int t = blockIdx.x, kc = blockIdx.y, tid = threadIdx.x;
    const float* src; int stride;
    if (t == 0)      { src = Wf;                stride = 32;  }
    else if (t == 1) { src = Wg;                stride = 32;  }
    else             { src = Wh + (t - 2) * 32; stride = 256; }

    const int c = tid & 31, a = tid >> 5;
    #pragma unroll
    for (int p = 0; p < 8; p++) {
        int kk = p * 8 + a;
        tile[kk][c] = src[(size_t)(kc * 64 + kk) * stride + c];
    }
    __syncthreads();
    const int kk = tid & 63, aa = tid >> 6;
    #pragma unroll
    for (int p = 0; p < 8; p++) {
        int cc = p * 4 + aa;
        WT[(size_t)(t * 32 + cc) * 256 + kc * 64 + kk] = (_Float16)tile[kk][cc];
    }
}

// ---------- proj v6: 1 tile/wave, batched reg-prefetch, no loop barriers -----
// grid (256, 5): x = row-group (64 rows), y = tile-pair. 4 waves:
// rowsub = wave&1 (32 rows), tile = blockIdx.y*2 + (wave>>1) (32 cols).
// Tiles 0,1 = f,g -> kf16/qf16; tiles 2-9 = h -> v_frag (MFMA-B global layout).
__global__ __launch_bounds__(256, 3) void proj_kernel(
    const float* __restrict__ x,
    const float* __restrict__ bfp, const float* __restrict__ bgp,
    const float* __restrict__ bhp,
    const _Float16* __restrict__ WT,
    _Float16* __restrict__ qf16, _Float16* __restrict__ kf16,
    unsigned short* __restrict__ v_frag)
{
    __shared__ __align__(16) _Float16 xs[64 * 256];            // 32 KB, swizzled
    __shared__ __align__(16) unsigned short tbuf[4][32 * 40];  // 10 KB

    const int tid  = threadIdx.x;
    const int lane = tid & 63;
    const int wave = tid >> 6;
    const int m_   = lane & 31;
    const int k8   = lane >> 5;
    const int row0 = blockIdx.x * 64;
    const int b    = row0 >> 12;
    const int n0   = row0 & 4095;
    const int kt   = n0 >> 6;

    // stage x -> f16, swizzled MFMA-A layout
    #pragma unroll
    for (int i = 0; i < 8; i++) {
        int r  = 8 * i + (tid >> 5);
        int c5 = tid & 31;
        const f32x4* src = (const f32x4*)(x + (size_t)(row0 + r) * 256 + c5 * 8);
        f32x4 a = src[0], c4 = src[1];
        f16x8 h = { (_Float16)a.x, (_Float16)a.y, (_Float16)a.z, (_Float16)a.w,
                    (_Float16)c4.x, (_Float16)c4.y, (_Float16)c4.z, (_Float16)c4.w };
        int chunk = (((r >> 5) * 32 + c5)) * 32 + ((r & 31) ^ (c5 & 7));
        *(f16x8*)(xs + chunk * 8) = h;
    }
    __syncthreads();

    const int rowsub = wave & 1;
    const int tile   = blockIdx.y * 2 + (wave >> 1);
    const _Float16* wb = WT + (size_t)(tile * 32 + m_) * 256 + k8 * 8;

    f32x16 acc;
    #pragma unroll
    for (int i = 0; i < 16; i++) acc[i] = 0.f;

    // batch-4 B prefetch, fully unrolled K-loop (no barriers)
    f16x8 Bb[2][4];
    #pragma unroll
    for (int j = 0; j < 4; j++) Bb[0][j] = *(const f16x8*)(wb + j * 16);
    #pragma unroll
    for (int g4 = 0; g4 < 4; g4++) {
        const int cur = g4 & 1, nxt = cur ^ 1;
        if (g4 < 3)
            #pragma unroll
            for (int j = 0; j < 4; j++)
                Bb[nxt][j] = *(const f16x8*)(wb + (g4 * 4 + 4 + j) * 16);
        #pragma unroll
        for (int j = 0; j < 4; j++) {
            int ks = g4 * 4 + j;
            f16x8 A = *(const f16x8*)(xs + ((rowsub * 32 + ks * 2 + k8) * 32
                                            + (m_ ^ ((ks * 2 + k8) & 7))) * 8);
            acc = __builtin_amdgcn_mfma_f32_32x32x16_f16(A, Bb[cur][j], acc, 0, 0, 0);
        }
    }

    if (tile < 2) {            // f -> kf16, g -> qf16
        float bias = (tile == 0) ? bfp[m_] : bgp[m_];
        _Float16* dst = (tile == 0) ? kf16 : qf16;
        #pragma unroll
        for (int r = 0; r < 16; r++) {
            int m = (r & 3) + 8 * (r >> 2) + 4 * k8;
            int row = row0 + rowsub * 32 + m;
            dst[(size_t)row * 32 + m_] = (_Float16)(acc[r] + bias);
        }
    } else {                   // h -> v_frag[b][chg][kt][oct][chsl][ch32][key8]
        const int ht   = tile - 2;
        const int chgv = ht >> 2, chslv = ht & 3;
        float bias = bhp[ht * 32 + m_];
        unsigned short* buf = tbuf[wave];
        #pragma unroll
        for (int u = 0; u < 8; u++) {
            int r = 2 * u;
            int m = (r & 3) + 8 * (r >> 2) + 4 * k8;   // key index (even)
            uint32_t v = (uint32_t)f2bf(acc[r] + bias)
                       | ((uint32_t)f2bf(acc[r + 1] + bias) << 16);
            *(uint32_t*)(buf + m_ * 40 + m) = v;       // [ch m_][keys m,m+1]
        }
        // same-wave write->read: lgkmcnt ordering suffices
        #pragma unroll
        for (int u = 0; u < 2; u++) {
            int idx2 = u * 64 + lane;
            int chr = idx2 >> 2, q8 = idx2 & 3;
            s16x8 vv = *(const s16x8*)(buf + chr * 40 + q8 * 8);
            int oct = rowsub * 4 + q8;
            size_t e = (((((size_t)(b * 2 + chgv) * 64 + kt) * 8 + oct) * 4
                          + chslv) * 32 + chr) * 8;
            *(s16x8*)(v_frag + e) = vv;
        }
    }
}

// ---------- flash attention v6: register B-frags from v_frag, LDS = P only ---
// grid (64 qt, 2 chg, 4 b) = 512 blocks, 512 thr = 8 waves.
// S-duty (waves 0-3): qsub = w&1, ksub = w>>1 -> S(32q x 32keys) -> P LDS.
// PV (all 8): qsub = w&1, chsl = w>>1 -> O(32q x 32ch), Bv direct from global.
__global__ __launch_bounds__(512, 4) void attn_kernel(
    const _Float16* __restrict__ qf16, const _Float16* __restrict__ kf16,
    const unsigned short* __restrict__ v_frag,
    const float* __restrict__ x, const float* __restrict__ gamma_p,
    float* __restrict__ out)
{
    __shared__ __align__(16) unsigned short P_s[2][2048];   // [qsub][oct][q^swz][8]
    __shared__ float l_s[2][2][32];                         // [qsub][ksub][q]

    const int tid  = threadIdx.x;
    const int lane = tid & 63;
    const int wave = tid >> 6;
    const int qsub = wave & 1;
    const int chsl = wave >> 1;       // PV channel slice (0..3)
    const int m_   = lane & 31;
    const int k8   = lane >> 5;
    const int qt   = blockIdx.x;
    const int chg  = blockIdx.y;
    const int b    = blockIdx.z;
    const size_t bn = (size_t)b * N_;
    const int ch0  = chg * 128;
    const bool is_s = (wave < 4);
    const int ksub  = wave >> 1;      // valid for S-waves

    // v_frag per-lane base: + kt*8192 + kstep*2048 per use
    const unsigned short* vb = v_frag + (size_t)(b * 2 + chg) * 524288
                             + (size_t)k8 * 1024 + chsl * 256 + m_ * 8;

    // Q & K fragments (S-waves)
    f16x8 Aq0, Aq1, Kc0, Kc1;
    if (is_s) {
        const int qrow = qt * 64 + qsub * 32 + m_;
        Aq0 = *(const f16x8*)(qf16 + (bn + qrow) * 32 + k8 * 8);
        Aq1 = *(const f16x8*)(qf16 + (bn + qrow) * 32 + 16 + k8 * 8);
        const _Float16* kp = kf16 + (bn + ksub * 32 + m_) * 32;
        Kc0 = *(const f16x8*)(kp + k8 * 8);
        Kc1 = *(const f16x8*)(kp + 16 + k8 * 8);
    }

    f32x16 acc;
    float l_acc[16];
    #pragma unroll
    for (int i = 0; i < 16; i++) { acc[i] = 0.f; l_acc[i] = 0.f; }

    for (int kt = 0; kt < N_ / 64; kt++) {
        const int ktn = (kt < 63) ? kt + 1 : 63;
        // PV B-fragments for THIS tile -> registers (independent of P)
        bf16x8 Bv[4];
        #pragma unroll
        for (int kstep = 0; kstep < 4; kstep++)
            Bv[kstep] = *(const bf16x8*)(vb + (size_t)kt * 8192 + kstep * 2048);
        // K prefetch for next tile (S-waves)
        f16x8 Kn0, Kn1;
        if (is_s) {
            const _Float16* kp = kf16 + (bn + ktn * 64 + ksub * 32 + m_) * 32;
            Kn0 = *(const f16x8*)(kp + k8 * 8);
            Kn1 = *(const f16x8*)(kp + 16 + k8 * 8);
        }
        if (is_s) {
            // S = Q K^T for this wave's 32-key half
            f32x16 s;
            #pragma unroll
            for (int i = 0; i < 16; i++) s[i] = 0.f;
            s = __builtin_amdgcn_mfma_f32_32x32x16_f16(Aq0, Kc0, s, 0, 0, 0);
            s = __builtin_amdgcn_mfma_f32_32x32x16_f16(Aq1, Kc1, s, 0, 0, 0);
            // fixed-offset exp2 softmax numerator; P -> LDS (b16, conflict-free)
            unsigned short* Pb = P_s[qsub];
            const int octet = ksub * 4 + (m_ >> 3);
            const int kofs = m_ & 7;
            #pragma unroll
            for (int r = 0; r < 16; r++) {
                float p = __builtin_amdgcn_exp2f(fmaf(s[r], LOG2E, -SOFT_OFF));
                l_acc[r] += p;
                int m = (r & 3) + 8 * (r >> 2) + 4 * k8;
                Pb[(octet * 32 + (m ^ (octet & 3))) * 8 + kofs] = f2bf_rh(p);
            }
        }
        __syncthreads();   // b1: P visible

        // PV: O += P V for (qsub, chsl), 4 ksteps over 64 keys
        const unsigned short* Pr = P_s[qsub];
        #pragma unroll
        for (int kstep = 0; kstep < 4; kstep++) {
            int oct = kstep * 2 + k8;
            bf16x8 Ap = *(const bf16x8*)(Pr + (oct * 32 + (m_ ^ (oct & 3))) * 8);
            acc = __builtin_amdgcn_mfma_f32_32x32x16_bf16(Ap, Bv[kstep], acc, 0, 0, 0);
        }
        if (is_s) { Kc0 = Kn0; Kc1 = Kn1; }
        __syncthreads();   // b2: P readers done before next overwrite
    }

    // l: reduce over 32 key-lanes, publish, combine across ksub halves
    if (is_s) {
        #pragma unroll
        for (int off = 1; off < 32; off <<= 1)
            #pragma unroll
            for (int r = 0; r < 16; r++)
                l_acc[r] += __shfl_xor(l_acc[r], off, 64);
        if (m_ == 0) {
            #pragma unroll
            for (int r = 0; r < 16; r++) {
                int q = (r & 3) + 8 * (r >> 2) + 4 * k8;
                l_s[qsub][ksub][q] = l_acc[r];
            }
        }
    }
    __syncthreads();

    const float gamma = *gamma_p;
    #pragma unroll
    for (int r = 0; r < 16; r++) {
        int q = (r & 3) + 8 * (r >> 2) + 4 * k8;
        float l = l_s[qsub][0][q] + l_s[qsub][1][q];
        size_t idx = (bn + qt * 64 + qsub * 32 + q) * 256 + ch0 + chsl * 32 + m_;
        out[idx] = gamma * (acc[r] / l) + x[idx];
    }
}

extern "C" void kernel_launch(void* const* d_in, const int* in_sizes, int n_in,
                              void* d_out, int out_size, void* d_ws, size_t ws_size,
                              hipStream_t stream) {
    const float* x   = (const float*)d_in[0];
    const float* Wf  = (const float*)d_in[1];
    const float* bfp = (const float*)d_in[2];
    const float* Wg  = (const float*)d_in[3];
    const float* bgp = (const float*)d_in[4];
    const float* Wh  = (const float*)d_in[5];
    const float* bhp = (const float*)d_in[6];
    const float* gam = (const float*)d_in[7];
    float* out = (float*)d_out;

    unsigned char* ws = (unsigned char*)d_ws;
    const size_t MB = 1 << 20;
    _Float16* WT    = (_Float16*)(ws);              // [320][256] f16, 160 KB
    _Float16* qf16  = (_Float16*)(ws + 1 * MB);     // [B*N][32] f16 (queries g)
    _Float16* kf16  = (_Float16*)(ws + 2 * MB);     // [B*N][32] f16 (keys f)
    unsigned short* v_frag = (unsigned short*)(ws + 3 * MB);  // 8.4 MB B-frag layout

    wprep<<<dim3(10, 4), dim3(256), 0, stream>>>(Wf, Wg, Wh, WT);
    proj_kernel<<<dim3(256, 5), dim3(256), 0, stream>>>(
        x, bfp, bgp, bhp, WT, qf16, kf16, v_frag);
    attn_kernel<<<dim3(64, 2, 4), dim3(512), 0, stream>>>(
        qf16, kf16, v_frag, x, gam, out);
}